// Round 1
// 1248.169 us; speedup vs baseline: 1.6026x; 1.6026x over previous
//
#include <hip/hip_runtime.h>
#include <math.h>

#define N_TOK   131072
#define HID     1024
#define CL      64
#define NEXP    64
#define KC      32      // K-chunk staged in LDS (double-buffered)
#define NC      (HID / KC)
#define TPW     16      // tokens per wave
#define TPB     64      // tokens per block (4 waves * 16)
#define TAU     3e-5f   // near-tie flag threshold (f32 distance error ~5e-6 -> 6x margin)

// ---- workspace layout (bytes) ----
#define WS_CNT   0                       // int
#define WS_LIST  16                      // int[N_TOK]
#define WS_CN    (16 + N_TOK * 4)        // float[NEXP*CL]
#define WS_CN2   (WS_CN + NEXP * CL * 4) // float[NEXP]
#define WS_CND   (WS_CN2 + NEXP * 4)     // double[NEXP*CL]  (offset % 8 == 0)
#define WS_CN2D  (WS_CND + NEXP * CL * 8)// double[NEXP]

__device__ __forceinline__ float wave_sum(float v) {
#pragma unroll
    for (int off = 32; off > 0; off >>= 1) v += __shfl_xor(v, off, 64);
    return v;
}
__device__ __forceinline__ double wave_sum_d(double v) {
#pragma unroll
    for (int off = 32; off > 0; off >>= 1) v += __shfl_xor(v, off, 64);
    return v;
}
__device__ __forceinline__ double wave_max_d(double v) {
#pragma unroll
    for (int off = 32; off > 0; off >>= 1) v = fmax(v, __shfl_xor(v, off, 64));
    return v;
}
// argmax over 64 lanes; ties -> lower index (matches jax.lax.top_k)
__device__ __forceinline__ void wave_argmax(float& v, int& idx) {
#pragma unroll
    for (int off = 32; off > 0; off >>= 1) {
        float v2 = __shfl_xor(v, off, 64);
        int   i2 = __shfl_xor(idx, off, 64);
        if (v2 > v || (v2 == v && i2 < idx)) { v = v2; idx = i2; }
    }
}
__device__ __forceinline__ void wave_argmax_d(double& v, int& idx) {
#pragma unroll
    for (int off = 32; off > 0; off >>= 1) {
        double v2 = __shfl_xor(v, off, 64);
        int    i2 = __shfl_xor(idx, off, 64);
        if (v2 > v || (v2 == v && i2 < idx)) { v = v2; idx = i2; }
    }
}

// async global->LDS, 16B per lane, LDS dest = wave-uniform base + lane*16
#define GLL16(gp, lp) __builtin_amdgcn_global_load_lds(                       \
    (const __attribute__((address_space(1))) void*)(gp),                      \
    (__attribute__((address_space(3))) void*)(lp), 16, 0, 0)

// Normalize centroids once (f64 master copy + f32 cast), zero flag counter.
extern "C" __global__ void prep_centroids(const float* __restrict__ cent,
                                          float* __restrict__ cn,
                                          float* __restrict__ cn2,
                                          double* __restrict__ cnd,
                                          double* __restrict__ cn2d,
                                          int* __restrict__ cnt) {
    int e = threadIdx.x;  // 64 threads, one expert each
    if (e == 0) *cnt = 0;
    double s = 0.0;
#pragma unroll
    for (int j = 0; j < CL; j++) { double v = (double)cent[e * CL + j]; s += v * v; }
    double nrm = fmax(sqrt(s), 1e-8);
    double s2 = 0.0;
#pragma unroll
    for (int j = 0; j < CL; j++) {
        double c = (double)cent[e * CL + j] / nrm;
        cnd[e * CL + j] = c;
        cn[e * CL + j] = (float)c;
        s2 += c * c;
    }
    cn2d[e] = s2;
    cn2[e] = (float)s2;
}

extern "C" __global__ void __launch_bounds__(256, 4)
router_main(const float* __restrict__ x, const float* __restrict__ W,
            const float* __restrict__ bias, const float* __restrict__ cn,
            const float* __restrict__ cn2, float* __restrict__ out,
            int* __restrict__ cnt, int* __restrict__ list) {
    // 16 KB x double-buffer + 16 KB W double-buffer = 32 KB -> 4-5 blocks/CU
    __shared__ float sX[2][TPB][KC];
    __shared__ float sW[2][KC][CL];

    const int tid  = threadIdx.x;
    const int lane = tid & 63;
    const int wv   = __builtin_amdgcn_readfirstlane(tid >> 6);  // wave-uniform
    const int tok0 = blockIdx.x * TPB;
    const int twave = tok0 + wv * TPW;

    // x staging: wave stages its own 16 tokens; 1 inst = 1 KB = 8 token-rows of 128B.
    // lane l -> token row (l>>3), byte offset (l&7)*16 within the row-chunk.
    const size_t xoff0 = (size_t)(twave + 0 + (lane >> 3)) * HID + (size_t)((lane & 7) * 4);
    const size_t xoff1 = (size_t)(twave + 8 + (lane >> 3)) * HID + (size_t)((lane & 7) * 4);
    // W staging: chunk tile = contiguous 8 KB; each wave copies 2 KB (2 insts).
    const int woffb = wv * 512 + lane * 4;  // floats

#define STAGE(buf, kc) do {                                                   \
        GLL16(x + xoff0 + (kc), &sX[buf][wv * TPW + 0][0]);                   \
        GLL16(x + xoff1 + (kc), &sX[buf][wv * TPW + 8][0]);                   \
        GLL16(W + (size_t)(kc) * CL + woffb,                                  \
              (char*)&sW[buf][0][0] + (wv * 2 + 0) * 1024);                   \
        GLL16(W + (size_t)(kc) * CL + woffb + 256,                            \
              (char*)&sW[buf][0][0] + (wv * 2 + 1) * 1024);                   \
    } while (0)

    float acc[TPW];
#pragma unroll
    for (int i = 0; i < TPW; i++) acc[i] = 0.f;

    STAGE(0, 0);
    for (int c = 0; c < NC; ++c) {
        __syncthreads();                       // chunk c landed (vmcnt0) + all waves off other buf
        if (c + 1 < NC) STAGE((c + 1) & 1, (c + 1) * KC);  // async; covered by compute below
        const int cur = c & 1;
        for (int k = 0; k < KC; k += 4) {
            const float w0 = sW[cur][k + 0][lane];   // lane-contiguous: conflict-free
            const float w1 = sW[cur][k + 1][lane];
            const float w2 = sW[cur][k + 2][lane];
            const float w3 = sW[cur][k + 3][lane];
#pragma unroll
            for (int i = 0; i < TPW; i++) {
                const float4 xv = *(const float4*)&sX[cur][wv * TPW + i][k];  // broadcast
                acc[i] = fmaf(xv.x, w0, acc[i]);
                acc[i] = fmaf(xv.y, w1, acc[i]);
                acc[i] = fmaf(xv.z, w2, acc[i]);
                acc[i] = fmaf(xv.w, w3, acc[i]);
            }
        }
    }
    __syncthreads();   // all waves done with sX before aliasing it as sD

    // epilogue: gelu (exact), l2-normalize across the 64 lanes (= cluster dims)
    float (*sD)[CL] = (float (*)[CL]) & sX[0][0][0];  // 64x64 f32 = 16 KB alias over sX

    const float bj = bias[lane];
    const float myCn2 = cn2[lane];
    float d2[TPW];
#pragma unroll
    for (int i = 0; i < TPW; i++) {
        float h = acc[i] + bj;
        float g = 0.5f * h * (1.f + erff(h * 0.70710678118654752440f));
        float n2 = wave_sum(g * g);
        float nrm = fmaxf(sqrtf(n2), 1e-8f);
        float d = g / nrm;
        d2[i] = wave_sum(d * d);
        sD[wv * TPW + i][lane] = d;   // rows are wave-private: no barrier needed
    }

    // distances: lane = expert; centroid row from global (16 KB, L1/L2-resident),
    // hoisted out of the token loop; d broadcast from LDS.
    float dot[TPW];
#pragma unroll
    for (int i = 0; i < TPW; i++) dot[i] = 0.f;
    const float* crow = cn + (size_t)lane * CL;
    for (int j = 0; j < CL; j += 4) {
        const float4 c4 = *(const float4*)(crow + j);
#pragma unroll
        for (int i = 0; i < TPW; i++) {
            const float4 d4 = *(const float4*)&sD[wv * TPW + i][j];  // broadcast
            dot[i] = fmaf(d4.x, c4.x, fmaf(d4.y, c4.y,
                     fmaf(d4.z, c4.z, fmaf(d4.w, c4.w, dot[i]))));
        }
    }

#pragma unroll 1
    for (int i = 0; i < TPW; i++) {
        float sq   = d2[i] + myCn2 - 2.f * dot[i];
        float dist = sqrtf(fmaxf(sq, 0.f));
        float nd   = -dist;

        // top-3 on negative distance (ordering identical to softmax probs)
        float a1 = nd; int j1 = lane; wave_argmax(a1, j1);
        float nd2m = (lane == j1) ? -1e30f : nd;
        float a2 = nd2m; int j2 = lane; wave_argmax(a2, j2);
        float nd3m = (lane == j2) ? -1e30f : nd2m;
        float a3 = nd3m; int j3 = lane; wave_argmax(a3, j3);

        float e    = expf(nd - a1);
        float ssum = wave_sum(e);
        float p    = e / ssum;
        float p1   = __shfl(p, j1, 64);
        float p2   = __shfl(p, j2, 64);

        bool flag = ((a1 - a2) < TAU) || ((a2 - a3) < TAU);

        if (lane == 0) {
            size_t t = (size_t)(twave + i);
            out[t * 2 + 0] = p1;
            out[t * 2 + 1] = p2;
            out[(size_t)N_TOK * 2 + t * 2 + 0] = (float)j1;
            out[(size_t)N_TOK * 2 + t * 2 + 1] = (float)j2;
            if (flag) { int ix = atomicAdd(cnt, 1); list[ix] = (int)t; }
        }
    }
#undef STAGE
}

// fp64 rescue for near-tie tokens: 1 wave per token, overwrites its 4 outputs.
extern "C" __global__ void __launch_bounds__(64)
router_rescue(const float* __restrict__ x, const float* __restrict__ W,
              const float* __restrict__ bias, const double* __restrict__ cnd,
              const double* __restrict__ cn2d, const int* __restrict__ list,
              const int* __restrict__ cnt, float* __restrict__ out) {
    __shared__ float  sx[HID];
    __shared__ double sd[CL];
    const int lane = threadIdx.x;
    const int n = *cnt;

    for (int fi = blockIdx.x; fi < n; fi += gridDim.x) {
        __syncthreads();
        const int t = list[fi];
        for (int k = lane; k < HID; k += 64) sx[k] = x[(size_t)t * HID + k];
        __syncthreads();

        // h_lane = sum_k x_k * W[k][lane], f64, 4 partial accumulators
        double h0 = 0.0, h1 = 0.0, h2 = 0.0, h3 = 0.0;
        const float* Wp = W + lane;
        for (int k = 0; k < HID; k += 4) {
            h0 += (double)sx[k + 0] * (double)Wp[(k + 0) * CL];
            h1 += (double)sx[k + 1] * (double)Wp[(k + 1) * CL];
            h2 += (double)sx[k + 2] * (double)Wp[(k + 2) * CL];
            h3 += (double)sx[k + 3] * (double)Wp[(k + 3) * CL];
        }
        double h = (h0 + h1) + (h2 + h3) + (double)bias[lane];
        double g = 0.5 * h * (1.0 + erf(h * 0.70710678118654752440));
        double n2 = wave_sum_d(g * g);
        double nrm = fmax(sqrt(n2), 1e-8);
        double d = g / nrm;
        double d2 = wave_sum_d(d * d);
        sd[lane] = d;
        __syncthreads();

        double dot = 0.0;
        const double* ce = cnd + (size_t)lane * CL;
#pragma unroll 8
        for (int j = 0; j < CL; j++) dot += sd[j] * ce[j];

        double sq   = d2 + cn2d[lane] - 2.0 * dot;
        double dist = sqrt(fmax(sq, 0.0));
        double nd   = -dist;
        double m    = wave_max_d(nd);
        double e    = exp(nd - m);
        double ssum = wave_sum_d(e);
        double p    = e / ssum;

        double a1 = nd; int j1 = lane; wave_argmax_d(a1, j1);
        double ndm = (lane == j1) ? -1e300 : nd;
        double a2 = ndm; int j2 = lane; wave_argmax_d(a2, j2);
        double p1 = __shfl(p, j1, 64);
        double p2 = __shfl(p, j2, 64);

        if (lane == 0) {
            out[(size_t)t * 2 + 0] = (float)p1;
            out[(size_t)t * 2 + 1] = (float)p2;
            out[(size_t)N_TOK * 2 + (size_t)t * 2 + 0] = (float)j1;
            out[(size_t)N_TOK * 2 + (size_t)t * 2 + 1] = (float)j2;
        }
    }
}

extern "C" void kernel_launch(void* const* d_in, const int* in_sizes, int n_in,
                              void* d_out, int out_size, void* d_ws, size_t ws_size,
                              hipStream_t stream) {
    const float* x    = (const float*)d_in[0];
    const float* W    = (const float*)d_in[1];
    const float* bias = (const float*)d_in[2];
    const float* cent = (const float*)d_in[3];
    // k (d_in[4]) == 2, hardcoded

    char* wsb = (char*)d_ws;
    int*    cnt  = (int*)(wsb + WS_CNT);
    int*    list = (int*)(wsb + WS_LIST);
    float*  cn   = (float*)(wsb + WS_CN);
    float*  cn2  = (float*)(wsb + WS_CN2);
    double* cnd  = (double*)(wsb + WS_CND);
    double* cn2d = (double*)(wsb + WS_CN2D);
    float*  out  = (float*)d_out;

    prep_centroids<<<1, 64, 0, stream>>>(cent, cn, cn2, cnd, cn2d, cnt);
    router_main<<<N_TOK / TPB, 256, 0, stream>>>(x, W, bias, cn, cn2, out, cnt, list);
    router_rescue<<<4096, 64, 0, stream>>>(x, W, bias, cnd, cn2d, list, cnt, out);
}

// Round 2
// 1129.518 us; speedup vs baseline: 1.7709x; 1.1050x over previous
//
#include <hip/hip_runtime.h>
#include <math.h>

#define N_TOK   131072
#define HID     1024
#define CL      64
#define NEXP    64
#define KC      32      // K-chunk staged in LDS (double-buffered)
#define NC      (HID / KC)
#define TPB     256     // tokens per block (4 waves * 64)
#define TAU     3e-5f   // near-tie flag threshold (f32 distance error ~5e-6 -> 6x margin)

// ---- workspace layout (bytes) ----
#define WS_CNT   0                       // int
#define WS_LIST  16                      // int[N_TOK]
#define WS_CN    (16 + N_TOK * 4)        // float[NEXP*CL]
#define WS_CN2   (WS_CN + NEXP * CL * 4) // float[NEXP]
#define WS_CND   (WS_CN2 + NEXP * 4)     // double[NEXP*CL]  (offset % 8 == 0)
#define WS_CN2D  (WS_CND + NEXP * CL * 8)// double[NEXP]

__device__ __forceinline__ float wave_sum(float v) {
#pragma unroll
    for (int off = 32; off > 0; off >>= 1) v += __shfl_xor(v, off, 64);
    return v;
}
__device__ __forceinline__ double wave_sum_d(double v) {
#pragma unroll
    for (int off = 32; off > 0; off >>= 1) v += __shfl_xor(v, off, 64);
    return v;
}
__device__ __forceinline__ double wave_max_d(double v) {
#pragma unroll
    for (int off = 32; off > 0; off >>= 1) v = fmax(v, __shfl_xor(v, off, 64));
    return v;
}
// argmax over 64 lanes; ties -> lower index (matches jax.lax.top_k)
__device__ __forceinline__ void wave_argmax(float& v, int& idx) {
#pragma unroll
    for (int off = 32; off > 0; off >>= 1) {
        float v2 = __shfl_xor(v, off, 64);
        int   i2 = __shfl_xor(idx, off, 64);
        if (v2 > v || (v2 == v && i2 < idx)) { v = v2; idx = i2; }
    }
}
__device__ __forceinline__ void wave_argmax_d(double& v, int& idx) {
#pragma unroll
    for (int off = 32; off > 0; off >>= 1) {
        double v2 = __shfl_xor(v, off, 64);
        int    i2 = __shfl_xor(idx, off, 64);
        if (v2 > v || (v2 == v && i2 < idx)) { v = v2; idx = i2; }
    }
}

// async global->LDS, 16B per lane, LDS dest = wave-uniform base + lane*16
#define GLL16(gp, lp) __builtin_amdgcn_global_load_lds(                       \
    (const __attribute__((address_space(1))) void*)(gp),                      \
    (__attribute__((address_space(3))) void*)(lp), 16, 0, 0)

// Normalize centroids once (f64 master copy + f32 cast), zero flag counter.
extern "C" __global__ void prep_centroids(const float* __restrict__ cent,
                                          float* __restrict__ cn,
                                          float* __restrict__ cn2,
                                          double* __restrict__ cnd,
                                          double* __restrict__ cn2d,
                                          int* __restrict__ cnt) {
    int e = threadIdx.x;  // 64 threads, one expert each
    if (e == 0) *cnt = 0;
    double s = 0.0;
#pragma unroll
    for (int j = 0; j < CL; j++) { double v = (double)cent[e * CL + j]; s += v * v; }
    double nrm = fmax(sqrt(s), 1e-8);
    double s2 = 0.0;
#pragma unroll
    for (int j = 0; j < CL; j++) {
        double c = (double)cent[e * CL + j] / nrm;
        cnd[e * CL + j] = c;
        cn[e * CL + j] = (float)c;
        s2 += c * c;
    }
    cn2d[e] = s2;
    cn2[e] = (float)s2;
}

extern "C" __global__ void __launch_bounds__(256, 2)
router_main(const float* __restrict__ x, const float* __restrict__ W,
            const float* __restrict__ bias, const float* __restrict__ cn,
            const float* __restrict__ cn2, float* __restrict__ out,
            int* __restrict__ cnt, int* __restrict__ list) {
    // 64 KB x double-buffer + 16 KB W double-buffer = 80 KB -> 2 blocks/CU
    __shared__ float sX[2][TPB][KC];
    __shared__ float sW[2][KC][CL];

    const int tid  = threadIdx.x;
    const int lane = tid & 63;
    const int wv   = __builtin_amdgcn_readfirstlane(tid >> 6);  // wave-uniform
    const int tg   = lane >> 3;      // token group 0..7 (8 tokens each)
    const int dg   = lane & 7;       // dim group 0..7 (8 dims each)
    const int tok0 = blockIdx.x * TPB;

    // x staging: wave stages its own 64 token rows; 1 inst = 1 KB = 8 rows of 128B.
    const size_t xoff = (size_t)(tok0 + wv * 64 + (lane >> 3)) * HID + (size_t)((lane & 7) * 4);
    // W staging: chunk tile 8 KB = 8 insts (2/wave); 1 inst = 4 k-rows of 256B.
    const int woff = (wv * 8 + (lane >> 4)) * CL + (lane & 15) * 4;  // floats

#define STAGE(buf, kc) do {                                                   \
        _Pragma("unroll")                                                     \
        for (int q = 0; q < 8; ++q)                                           \
            GLL16(x + xoff + (size_t)q * 8 * HID + (kc),                      \
                  &sX[buf][wv * 64 + q * 8][0]);                              \
        GLL16(W + (size_t)(kc) * CL + woff,       &sW[buf][wv * 8][0]);       \
        GLL16(W + (size_t)(kc) * CL + woff + 256, &sW[buf][wv * 8 + 4][0]);   \
    } while (0)

    float acc[8][8];
#pragma unroll
    for (int t = 0; t < 8; ++t)
#pragma unroll
        for (int d = 0; d < 8; ++d) acc[t][d] = 0.f;

    STAGE(0, 0);
#pragma unroll 1
    for (int c = 0; c < NC; ++c) {
        __syncthreads();                       // chunk c landed; all waves off other buf
        if (c + 1 < NC) STAGE((c + 1) & 1, (c + 1) * KC);  // async; covered by compute
        const int cur = c & 1;
        const float* xb = &sX[cur][wv * 64 + tg * 8][0];   // lane's 8 token rows
        const float* wb = &sW[cur][0][dg * 8];             // lane's 8 dims
#pragma unroll
        for (int k4 = 0; k4 < KC / 4; ++k4) {
            float4 xq[8];
#pragma unroll
            for (int tt = 0; tt < 8; ++tt)
                xq[tt] = *(const float4*)(xb + tt * KC + k4 * 4);
#pragma unroll
            for (int kk = 0; kk < 4; ++kk) {
                const float4 wA = *(const float4*)(wb + (k4 * 4 + kk) * CL);
                const float4 wB = *(const float4*)(wb + (k4 * 4 + kk) * CL + 4);
#pragma unroll
                for (int tt = 0; tt < 8; ++tt) {
                    const float xv = (kk == 0) ? xq[tt].x : (kk == 1) ? xq[tt].y
                                   : (kk == 2) ? xq[tt].z : xq[tt].w;
                    acc[tt][0] = fmaf(xv, wA.x, acc[tt][0]);
                    acc[tt][1] = fmaf(xv, wA.y, acc[tt][1]);
                    acc[tt][2] = fmaf(xv, wA.z, acc[tt][2]);
                    acc[tt][3] = fmaf(xv, wA.w, acc[tt][3]);
                    acc[tt][4] = fmaf(xv, wB.x, acc[tt][4]);
                    acc[tt][5] = fmaf(xv, wB.y, acc[tt][5]);
                    acc[tt][6] = fmaf(xv, wB.z, acc[tt][6]);
                    acc[tt][7] = fmaf(xv, wB.w, acc[tt][7]);
                }
            }
        }
    }
    __syncthreads();   // all waves done with sX/sW before aliasing as sD/sN

    // ---- epilogue: gelu (exact) + l2-normalize; dims split across 8-lane groups
    const int d0   = dg * 8;
    const int trow = wv * 64 + tg * 8;   // first of this lane's 8 token rows

    const float4 b0 = *(const float4*)(bias + d0);
    const float4 b1 = *(const float4*)(bias + d0 + 4);
    const float bq[8] = {b0.x, b0.y, b0.z, b0.w, b1.x, b1.y, b1.z, b1.w};

    float g[8][8];
    float n2[8];
#pragma unroll
    for (int tt = 0; tt < 8; ++tt) {
        float s = 0.f;
#pragma unroll
        for (int dd = 0; dd < 8; ++dd) {
            float h = acc[tt][dd] + bq[dd];
            float gv = 0.5f * h * (1.f + erff(h * 0.70710678118654752440f));
            g[tt][dd] = gv;
            s = fmaf(gv, gv, s);
        }
        n2[tt] = s;
    }
#pragma unroll
    for (int tt = 0; tt < 8; ++tt) {   // reduce across the 8 dim-group lanes
        n2[tt] += __shfl_xor(n2[tt], 1, 64);
        n2[tt] += __shfl_xor(n2[tt], 2, 64);
        n2[tt] += __shfl_xor(n2[tt], 4, 64);
    }

    float (*sD)[CL] = (float (*)[CL])&sX[0][0][0];  // 256x64 f32 = 64 KB alias
    float* sN = (float*)&sW[0][0][0];               // 256 f32 token-norms alias

    float d2[8];
#pragma unroll
    for (int tt = 0; tt < 8; ++tt) {
        float nrm = fmaxf(sqrtf(n2[tt]), 1e-8f);
        float inv = 1.f / nrm;
        float4 w0, w1;
        w0.x = g[tt][0] * inv; w0.y = g[tt][1] * inv;
        w0.z = g[tt][2] * inv; w0.w = g[tt][3] * inv;
        w1.x = g[tt][4] * inv; w1.y = g[tt][5] * inv;
        w1.z = g[tt][6] * inv; w1.w = g[tt][7] * inv;
        float s2 = 0.f;
        s2 = fmaf(w0.x, w0.x, s2); s2 = fmaf(w0.y, w0.y, s2);
        s2 = fmaf(w0.z, w0.z, s2); s2 = fmaf(w0.w, w0.w, s2);
        s2 = fmaf(w1.x, w1.x, s2); s2 = fmaf(w1.y, w1.y, s2);
        s2 = fmaf(w1.z, w1.z, s2); s2 = fmaf(w1.w, w1.w, s2);
        *(float4*)&sD[trow + tt][d0]     = w0;
        *(float4*)&sD[trow + tt][d0 + 4] = w1;
        d2[tt] = s2;
    }
#pragma unroll
    for (int tt = 0; tt < 8; ++tt) {
        d2[tt] += __shfl_xor(d2[tt], 1, 64);
        d2[tt] += __shfl_xor(d2[tt], 2, 64);
        d2[tt] += __shfl_xor(d2[tt], 4, 64);
    }
    if (dg == 0) {
#pragma unroll
        for (int tt = 0; tt < 8; ++tt) sN[trow + tt] = d2[tt];
    }

    // ---- distances + top-k: lane = expert; 64 tokens per wave from LDS broadcast
    float4 cq[16];
#pragma unroll
    for (int j = 0; j < 16; ++j)
        cq[j] = *(const float4*)(cn + (size_t)lane * CL + j * 4);
    const float myCn2 = cn2[lane];
    const float* drow = &sD[wv * 64][0];

#pragma unroll 1
    for (int tl = 0; tl < 64; ++tl) {
        const float* dp = drow + tl * CL;
        float dot = 0.f;
#pragma unroll
        for (int j = 0; j < 16; ++j) {
            const float4 dv = *(const float4*)(dp + j * 4);   // broadcast
            dot = fmaf(dv.x, cq[j].x, fmaf(dv.y, cq[j].y,
                  fmaf(dv.z, cq[j].z, fmaf(dv.w, cq[j].w, dot))));
        }
        const float d2b = sN[wv * 64 + tl];

        float sq   = d2b + myCn2 - 2.f * dot;
        float dist = sqrtf(fmaxf(sq, 0.f));
        float nd   = -dist;

        // top-3 on negative distance (ordering identical to softmax probs)
        float a1 = nd; int j1 = lane; wave_argmax(a1, j1);
        float nd2m = (lane == j1) ? -1e30f : nd;
        float a2 = nd2m; int j2 = lane; wave_argmax(a2, j2);
        float nd3m = (lane == j2) ? -1e30f : nd2m;
        float a3 = nd3m; int j3 = lane; wave_argmax(a3, j3);

        float e    = expf(nd - a1);
        float ssum = wave_sum(e);
        float p    = e / ssum;
        float p1   = __shfl(p, j1, 64);
        float p2   = __shfl(p, j2, 64);

        bool flag = ((a1 - a2) < TAU) || ((a2 - a3) < TAU);

        if (lane == 0) {
            size_t t = (size_t)(tok0 + wv * 64 + tl);
            out[t * 2 + 0] = p1;
            out[t * 2 + 1] = p2;
            out[(size_t)N_TOK * 2 + t * 2 + 0] = (float)j1;
            out[(size_t)N_TOK * 2 + t * 2 + 1] = (float)j2;
            if (flag) { int ix = atomicAdd(cnt, 1); list[ix] = (int)t; }
        }
    }
#undef STAGE
}

// fp64 rescue for near-tie tokens: 1 wave per token, overwrites its 4 outputs.
extern "C" __global__ void __launch_bounds__(64)
router_rescue(const float* __restrict__ x, const float* __restrict__ W,
              const float* __restrict__ bias, const double* __restrict__ cnd,
              const double* __restrict__ cn2d, const int* __restrict__ list,
              const int* __restrict__ cnt, float* __restrict__ out) {
    __shared__ float  sx[HID];
    __shared__ double sd[CL];
    const int lane = threadIdx.x;
    const int n = *cnt;

    for (int fi = blockIdx.x; fi < n; fi += gridDim.x) {
        __syncthreads();
        const int t = list[fi];
        for (int k = lane; k < HID; k += 64) sx[k] = x[(size_t)t * HID + k];
        __syncthreads();

        // h_lane = sum_k x_k * W[k][lane], f64, 4 partial accumulators
        double h0 = 0.0, h1 = 0.0, h2 = 0.0, h3 = 0.0;
        const float* Wp = W + lane;
        for (int k = 0; k < HID; k += 4) {
            h0 += (double)sx[k + 0] * (double)Wp[(k + 0) * CL];
            h1 += (double)sx[k + 1] * (double)Wp[(k + 1) * CL];
            h2 += (double)sx[k + 2] * (double)Wp[(k + 2) * CL];
            h3 += (double)sx[k + 3] * (double)Wp[(k + 3) * CL];
        }
        double h = (h0 + h1) + (h2 + h3) + (double)bias[lane];
        double g = 0.5 * h * (1.0 + erf(h * 0.70710678118654752440));
        double n2 = wave_sum_d(g * g);
        double nrm = fmax(sqrt(n2), 1e-8);
        double d = g / nrm;
        double d2 = wave_sum_d(d * d);
        sd[lane] = d;
        __syncthreads();

        double dot = 0.0;
        const double* ce = cnd + (size_t)lane * CL;
#pragma unroll 8
        for (int j = 0; j < CL; j++) dot += sd[j] * ce[j];

        double sq   = d2 + cn2d[lane] - 2.0 * dot;
        double dist = sqrt(fmax(sq, 0.0));
        double nd   = -dist;
        double m    = wave_max_d(nd);
        double e    = exp(nd - m);
        double ssum = wave_sum_d(e);
        double p    = e / ssum;

        double a1 = nd; int j1 = lane; wave_argmax_d(a1, j1);
        double ndm = (lane == j1) ? -1e300 : nd;
        double a2 = ndm; int j2 = lane; wave_argmax_d(a2, j2);
        double p1 = __shfl(p, j1, 64);
        double p2 = __shfl(p, j2, 64);

        if (lane == 0) {
            out[(size_t)t * 2 + 0] = (float)p1;
            out[(size_t)t * 2 + 1] = (float)p2;
            out[(size_t)N_TOK * 2 + (size_t)t * 2 + 0] = (float)j1;
            out[(size_t)N_TOK * 2 + (size_t)t * 2 + 1] = (float)j2;
        }
    }
}

extern "C" void kernel_launch(void* const* d_in, const int* in_sizes, int n_in,
                              void* d_out, int out_size, void* d_ws, size_t ws_size,
                              hipStream_t stream) {
    const float* x    = (const float*)d_in[0];
    const float* W    = (const float*)d_in[1];
    const float* bias = (const float*)d_in[2];
    const float* cent = (const float*)d_in[3];
    // k (d_in[4]) == 2, hardcoded

    char* wsb = (char*)d_ws;
    int*    cnt  = (int*)(wsb + WS_CNT);
    int*    list = (int*)(wsb + WS_LIST);
    float*  cn   = (float*)(wsb + WS_CN);
    float*  cn2  = (float*)(wsb + WS_CN2);
    double* cnd  = (double*)(wsb + WS_CND);
    double* cn2d = (double*)(wsb + WS_CN2D);
    float*  out  = (float*)d_out;

    prep_centroids<<<1, 64, 0, stream>>>(cent, cn, cn2, cnd, cn2d, cnt);
    router_main<<<N_TOK / TPB, 256, 0, stream>>>(x, W, bias, cn, cn2, out, cnt, list);
    router_rescue<<<4096, 64, 0, stream>>>(x, W, bias, cnd, cn2d, list, cnt, out);
}